// Round 4
// baseline (188.612 us; speedup 1.0000x reference)
//
#include <hip/hip_runtime.h>
#include <math.h>

// Problem constants (reference: N=64, H=512, W=512, RATIO=2, ITERATIONS=1)
#define NIMG 64
#define HH 512
#define WW 512
#define SH 8                           // rows per wave
#define NBLOCKS (NIMG * 32)            // 2048 blocks x 4 waves = 8192 waves
#define INV_TOTAL (1.0f / 16777216.0f) // 1/(64*512*512), exact pow2

typedef unsigned int u32;

// Flag byte per pixel: bit0 = (y>0), bit1 = (y==0), 0x00 = invalid/halo.
// cv2 morphology with border clipping: border = has_one & has_zero over the
// valid 3x3 window; invalid cells contribute to neither bit.
__device__ __forceinline__ u32 flags4(int4 yv) {
    u32 f = (yv.x > 0) ? 1u : 2u;
    f |= ((yv.y > 0) ? 1u : 2u) << 8;
    f |= ((yv.z > 0) ? 1u : 2u) << 16;
    f |= ((yv.w > 0) ? 1u : 2u) << 24;
    return f;
}

// One wave = 256 cols (4 px/lane) x SH rows. No LDS tile, no barrier, no
// ballot: packed-byte morphology in VGPRs, cross-lane bytes via bpermute,
// one scalar load/row for the single interior boundary column (255 or 256).
__global__ __launch_bounds__(256, 8) void border_loss_main(
    const float* __restrict__ x, const int* __restrict__ y,
    float* __restrict__ part, int atomic_mode)
{
    __shared__ float wsum[4];

    const int tid  = threadIdx.x;
    const int lane = tid & 63;
    const int w    = tid >> 6;                // wave 0..3
    const int b    = blockIdx.x;
    const int n    = b >> 5;                  // image (32 blocks/image)
    const int q    = ((b & 31) << 2) | w;     // wave slot 0..127 in image
    const int g    = q & 1;                   // column group (0: cols 0-255)
    const int R0   = (q >> 1) * SH;           // first row of strip
    const int base = n * (HH * WW);           // < 2^24, int-safe
    const int colv = (g << 8) | (lane << 2);  // lane's first col (16B aligned)
    const int cb   = 256 - g;                 // boundary col: g=0->256, g=1->255
    const int*   __restrict__ yb = y + base;
    const float* __restrict__ xb = x + base;
    const int idxL = (lane + 63) & 63;        // hoisted bpermute indices
    const int idxR = (lane + 1) & 63;

#define YVEC(row) (*(const int4*)(yb + (row) * WW + colv))
#define XVEC(row) (*(const float4*)(xb + (row) * WW + colv))
#define YBND(row) (yb[__builtin_amdgcn_readfirstlane((row) * WW + cb)])

    // ---- window init: rows R0-1 (halo), R0; prefetch row R0+1 raw.
    u32 f_t = 0u, bF_t = 0u;
    if (R0 > 0) {                             // wave-uniform
        f_t  = flags4(YVEC(R0 - 1));
        bF_t = (YBND(R0 - 1) > 0) ? 1u : 2u;
    }
    u32 f_c  = flags4(YVEC(R0));
    u32 bF_c = (YBND(R0) > 0) ? 1u : 2u;

    const int pr0 = (R0 + 1 < HH) ? R0 + 1 : HH - 1;
    int4   y4_b = YVEC(pr0);
    int    bY_b = YBND(pr0);
    float4 x4_c = XVEC(R0);

    float acc0 = 0.0f, acc1 = 0.0f;

    #pragma unroll
    for (int r = 0; r < SH; ++r) {
        const int gr = R0 + r;

        // prefetch for next iteration (compile-time dead in last iter)
        int4 y4_n; int bY_n; float4 x4_n;
        if (r < SH - 1) {
            const int pry = (gr + 2 < HH) ? gr + 2 : HH - 1;
            y4_n = YVEC(pry);
            bY_n = YBND(pry);
            x4_n = XVEC(gr + 1);
        }

        // consume prefetched bottom row (gr+1); invalid past image -> 0
        const bool vB = (gr + 1 < HH);
        const u32 f_b  = vB ? flags4(y4_b) : 0u;
        const u32 bF_b = vB ? ((bY_b > 0) ? 1u : 2u) : 0u;

        // vertical OR (1 op per 4 px), then horizontal 3-window OR
        const u32 v   = f_t | f_c | f_b;
        const u32 bFv = bF_t | bF_c | bF_b;   // boundary col, vertical OR
        const u32 vL  = __shfl(v, idxL);      // left lane's v (wrap)
        const u32 vR  = __shfl(v, idxR);
        const u32 inL = (lane == 0)  ? (g ? bFv : 0u) : (vL >> 24);
        const u32 inR = (lane == 63) ? (g ? 0u : bFv) : (vR & 0xffu);
        const u32 h   = v | (v << 8) | (v >> 8) | inL | (inR << 24);
        const u32 bm  = h & (h >> 1) & 0x01010101u;  // border bit per byte

        // per-pixel loss: max(x,0) - x*m + ln(1+e^{-|x|})   (hw exp/log)
        const float xs[4] = {x4_c.x, x4_c.y, x4_c.z, x4_c.w};
        #pragma unroll
        for (int k = 0; k < 4; ++k) {
            const float xf = xs[k];
            const float lg = __logf(1.0f + __expf(-fabsf(xf)));
            const bool mbit = (f_c >> (8 * k)) & 1u;
            const bool bbit = (bm  >> (8 * k)) & 1u;
            const float loss = fmaxf(xf, 0.0f) - (mbit ? xf : 0.0f) + lg;
            if (k & 1) acc1 = fmaf(loss, bbit ? 2.0f : 1.0f, acc1);
            else       acc0 = fmaf(loss, bbit ? 2.0f : 1.0f, acc0);
        }

        // roll window
        f_t = f_c;  f_c = f_b;
        bF_t = bF_c; bF_c = bF_b;
        if (r < SH - 1) { y4_b = y4_n; bY_b = bY_n; x4_c = x4_n; }
    }
#undef YVEC
#undef XVEC
#undef YBND

    // ---- reduction: wave shuffle + tiny LDS across 4 waves
    float acc = acc0 + acc1;
    #pragma unroll
    for (int off = 32; off > 0; off >>= 1)
        acc += __shfl_down(acc, off);
    if (lane == 0) wsum[w] = acc;
    __syncthreads();
    if (tid == 0) {
        const float t = wsum[0] + wsum[1] + wsum[2] + wsum[3];
        if (atomic_mode) atomicAdd(part, t * INV_TOTAL);
        else             part[blockIdx.x] = t;
    }
}

__global__ __launch_bounds__(256) void border_loss_reduce(
    const float* __restrict__ part, float* __restrict__ out)
{
    __shared__ float wsum[4];
    float t = 0.0f;
    for (int i = threadIdx.x; i < NBLOCKS; i += 256) t += part[i];
    #pragma unroll
    for (int off = 32; off > 0; off >>= 1)
        t += __shfl_down(t, off);
    if ((threadIdx.x & 63) == 0) wsum[threadIdx.x >> 6] = t;
    __syncthreads();
    if (threadIdx.x == 0)
        out[0] = (wsum[0] + wsum[1] + wsum[2] + wsum[3]) * INV_TOTAL;
}

__global__ void border_loss_zero(float* out) { out[0] = 0.0f; }

extern "C" void kernel_launch(void* const* d_in, const int* in_sizes, int n_in,
                              void* d_out, int out_size, void* d_ws, size_t ws_size,
                              hipStream_t stream)
{
    const float* x = (const float*)d_in[0];
    const int*   y = (const int*)d_in[1];
    float* out = (float*)d_out;

    if (ws_size >= (size_t)NBLOCKS * sizeof(float)) {
        // Deterministic two-stage reduction via workspace partials.
        float* part = (float*)d_ws;
        border_loss_main<<<NBLOCKS, 256, 0, stream>>>(x, y, part, 0);
        border_loss_reduce<<<1, 256, 0, stream>>>(part, out);
    } else {
        // Fallback: zero output then atomic accumulation.
        border_loss_zero<<<1, 1, 0, stream>>>(out);
        border_loss_main<<<NBLOCKS, 256, 0, stream>>>(x, y, out, 1);
    }
}

// Round 5
// 143.655 us; speedup vs baseline: 1.3129x; 1.3129x over previous
//
#include <hip/hip_runtime.h>
#include <math.h>

// Problem constants (reference: N=64, H=512, W=512, RATIO=2, ITERATIONS=1)
#define NIMG 64
#define HH 512
#define WW 512
#define TR 16                          // output rows per block
#define LR (TR + 2)                    // staged rows incl. vertical halo = 18
#define LSTRIDE 130                    // u32 per LDS row: 128 data + 2 pad cols
#define NBLOCKS (NIMG * (HH / TR))     // 64*32 = 2048
#define INV_TOTAL (1.0f / 16777216.0f) // 1/(64*512*512), exact pow2

typedef unsigned int u32;
typedef unsigned long long u64;

// Flag byte per pixel: bit0 = (y>0), bit1 = (y==0), 0x00 = invalid/halo.
// cv2-clipped-border morphology: border = has_one & has_zero over the valid
// 3x3 window; invalid (out-of-image) cells contribute to NEITHER bit, which
// the 0x00 sentinel rows/pad-columns implement exactly.
__device__ __forceinline__ u32 flags4(int4 yv) {
    u32 f = (yv.x > 0) ? 1u : 2u;
    f |= ((yv.y > 0) ? 1u : 2u) << 8;
    f |= ((yv.z > 0) ? 1u : 2u) << 16;
    f |= ((yv.w > 0) ? 1u : 2u) << 24;
    return f;
}

__global__ __launch_bounds__(256, 8) void border_loss_main(
    const float* __restrict__ x, const int* __restrict__ y,
    float* __restrict__ part, int atomic_mode)
{
    __shared__ __align__(16) u32 flags[LR][LSTRIDE];   // 18*130*4 = 9360 B
    __shared__ float wsum[4];

    const int tid  = threadIdx.x;
    const int lane = tid & 63;
    const int wv   = tid >> 6;
    const int b    = blockIdx.x;
    const int n    = b >> 5;                 // image (32 strips/image)
    const int R0   = (b & 31) * TR;          // first output row of strip
    const int base = n * (HH * WW);          // < 2^24, int-safe
    const int*   __restrict__ yb = y + base;
    const float* __restrict__ xb = x + base;

    // ---- zero the pad columns (sentinel = invalid)
    if (tid < 2 * LR) {
        flags[tid >> 1][(tid & 1) ? (LSTRIDE - 1) : 0] = 0u;
    }

    // ---- Phase 1: stage flags for rows R0-1 .. R0+TR  (18 x 128 u32 tasks)
    // 2304 tasks / 256 threads = 9 independent iterations; each wave's 64
    // lanes share one row (branch wave-uniform), contiguous int4 loads.
    for (int it = 0; it < 9; ++it) {
        const int idx = tid + (it << 8);
        const int j   = idx >> 7;            // LDS row 0..17
        const int g   = idx & 127;           // u32 group (4 px)
        const int gr  = R0 - 1 + j;          // global row
        u32 f = 0u;
        if ((unsigned)gr < (unsigned)HH) {
            const int4 yv = *(const int4*)(yb + gr * WW + (g << 2));
            f = flags4(yv);
        }
        flags[j][g + 1] = f;
    }
    __syncthreads();

    // ---- Phase 2: 16 rows x 64 eight-px chunks = 1024 tasks, 4 iterations.
    float acc = 0.0f;
    for (int it = 0; it < 4; ++it) {
        const int idx = tid + (it << 8);
        const int r   = idx >> 6;            // row offset 0..15 (wave-uniform)
        const int c   = idx & 63;            // 8-px chunk = lane
        const int jt  = r;                   // LDS rows r, r+1, r+2
        const int d   = c << 1;              // pad-dword index of left word

        // 6 aligned 8B LDS reads: words [d..d+1] and [d+2..d+3] per row
        const u64 t0 = *(const u64*)&flags[jt    ][d];
        const u64 t1 = *(const u64*)&flags[jt    ][d + 2];
        const u64 c0 = *(const u64*)&flags[jt + 1][d];
        const u64 c1 = *(const u64*)&flags[jt + 1][d + 2];
        const u64 b0 = *(const u64*)&flags[jt + 2][d];
        const u64 b1 = *(const u64*)&flags[jt + 2][d + 2];

        // x for the 8 center px (cols 8c..8c+7 of row R0+r)
        const float* xr = xb + (R0 + r) * WW + (c << 3);
        const float4 xa = *(const float4*)(xr);
        const float4 xd = *(const float4*)(xr + 4);

        // vertical OR
        const u64 A = t0 | c0 | b0;          // bytes: cols 8c-4 .. 8c+3
        const u64 B = t1 | c1 | b1;          // bytes: cols 8c+4 .. 8c+11
        // center 8 bytes and 3-wide horizontal OR with edge-in bytes
        const u64 cen = (A >> 32) | (B << 32);
        const u64 lb  = (A >> 24) & 0xffull;             // col 8c-1
        const u64 rb  = ((B >> 32) & 0xffull) << 56;     // col 8c+8
        const u64 h   = cen | (cen << 8) | (cen >> 8) | lb | rb;
        const u64 border = h & (h >> 1) & 0x0101010101010101ull;
        const u64 m64    = (c0 >> 32) | (c1 << 32);      // center-row m bits

        // per-pixel: max(x,0) - x*m + ln(1+e^{-|x|}); weight 2 on border
        {
            const float xf = xa.x;
            const float lg = __logf(1.0f + __expf(-fabsf(xf)));
            const float ls = fmaxf(xf, 0.0f) - ((m64 & 1ull) ? xf : 0.0f) + lg;
            acc = fmaf(ls, (border & 1ull) ? 2.0f : 1.0f, acc);
        }
        {
            const float xf = xa.y;
            const float lg = __logf(1.0f + __expf(-fabsf(xf)));
            const float ls = fmaxf(xf, 0.0f) - ((m64 >> 8 & 1ull) ? xf : 0.0f) + lg;
            acc = fmaf(ls, (border >> 8 & 1ull) ? 2.0f : 1.0f, acc);
        }
        {
            const float xf = xa.z;
            const float lg = __logf(1.0f + __expf(-fabsf(xf)));
            const float ls = fmaxf(xf, 0.0f) - ((m64 >> 16 & 1ull) ? xf : 0.0f) + lg;
            acc = fmaf(ls, (border >> 16 & 1ull) ? 2.0f : 1.0f, acc);
        }
        {
            const float xf = xa.w;
            const float lg = __logf(1.0f + __expf(-fabsf(xf)));
            const float ls = fmaxf(xf, 0.0f) - ((m64 >> 24 & 1ull) ? xf : 0.0f) + lg;
            acc = fmaf(ls, (border >> 24 & 1ull) ? 2.0f : 1.0f, acc);
        }
        {
            const float xf = xd.x;
            const float lg = __logf(1.0f + __expf(-fabsf(xf)));
            const float ls = fmaxf(xf, 0.0f) - ((m64 >> 32 & 1ull) ? xf : 0.0f) + lg;
            acc = fmaf(ls, (border >> 32 & 1ull) ? 2.0f : 1.0f, acc);
        }
        {
            const float xf = xd.y;
            const float lg = __logf(1.0f + __expf(-fabsf(xf)));
            const float ls = fmaxf(xf, 0.0f) - ((m64 >> 40 & 1ull) ? xf : 0.0f) + lg;
            acc = fmaf(ls, (border >> 40 & 1ull) ? 2.0f : 1.0f, acc);
        }
        {
            const float xf = xd.z;
            const float lg = __logf(1.0f + __expf(-fabsf(xf)));
            const float ls = fmaxf(xf, 0.0f) - ((m64 >> 48 & 1ull) ? xf : 0.0f) + lg;
            acc = fmaf(ls, (border >> 48 & 1ull) ? 2.0f : 1.0f, acc);
        }
        {
            const float xf = xd.w;
            const float lg = __logf(1.0f + __expf(-fabsf(xf)));
            const float ls = fmaxf(xf, 0.0f) - ((m64 >> 56 & 1ull) ? xf : 0.0f) + lg;
            acc = fmaf(ls, (border >> 56 & 1ull) ? 2.0f : 1.0f, acc);
        }
    }

    // ---- reduction: wave shuffle + tiny LDS across 4 waves
    #pragma unroll
    for (int off = 32; off > 0; off >>= 1)
        acc += __shfl_down(acc, off);
    __syncthreads();                         // flags tile dead; reuse barrier
    if (lane == 0) wsum[wv] = acc;
    __syncthreads();
    if (tid == 0) {
        const float t = wsum[0] + wsum[1] + wsum[2] + wsum[3];
        if (atomic_mode) atomicAdd(part, t * INV_TOTAL);
        else             part[blockIdx.x] = t;
    }
}

__global__ __launch_bounds__(256) void border_loss_reduce(
    const float* __restrict__ part, float* __restrict__ out)
{
    __shared__ float wsum[4];
    float t = 0.0f;
    for (int i = threadIdx.x; i < NBLOCKS; i += 256) t += part[i];
    #pragma unroll
    for (int off = 32; off > 0; off >>= 1)
        t += __shfl_down(t, off);
    if ((threadIdx.x & 63) == 0) wsum[threadIdx.x >> 6] = t;
    __syncthreads();
    if (threadIdx.x == 0)
        out[0] = (wsum[0] + wsum[1] + wsum[2] + wsum[3]) * INV_TOTAL;
}

__global__ void border_loss_zero(float* out) { out[0] = 0.0f; }

extern "C" void kernel_launch(void* const* d_in, const int* in_sizes, int n_in,
                              void* d_out, int out_size, void* d_ws, size_t ws_size,
                              hipStream_t stream)
{
    const float* x = (const float*)d_in[0];
    const int*   y = (const int*)d_in[1];
    float* out = (float*)d_out;

    if (ws_size >= (size_t)NBLOCKS * sizeof(float)) {
        // Deterministic two-stage reduction via workspace partials.
        float* part = (float*)d_ws;
        border_loss_main<<<NBLOCKS, 256, 0, stream>>>(x, y, part, 0);
        border_loss_reduce<<<1, 256, 0, stream>>>(part, out);
    } else {
        // Fallback: zero output then atomic accumulation.
        border_loss_zero<<<1, 1, 0, stream>>>(out);
        border_loss_main<<<NBLOCKS, 256, 0, stream>>>(x, y, out, 1);
    }
}